// Round 1
// baseline (451.360 us; speedup 1.0000x reference)
//
#include <hip/hip_runtime.h>

#define S_LEN 2048
#define DMODEL 1024
#define NHEADS 16
#define MLPDIM 4096

typedef float f32x4 __attribute__((ext_vector_type(4)));
typedef __bf16 bf16x8 __attribute__((ext_vector_type(8)));
typedef __bf16 bf16x4 __attribute__((ext_vector_type(4)));

__device__ __forceinline__ void gload_lds16(const void* gsrc, void* ldst) {
  __builtin_amdgcn_global_load_lds(
      (const __attribute__((address_space(1))) void*)gsrc,
      (__attribute__((address_space(3))) void*)ldst, 16, 0, 0);
}

// ---------------- transpose + f32->bf16 cast: in [K][N] f32 -> out [N][K] bf16
__global__ __launch_bounds__(256) void transpose_cast_k(
    const float* __restrict__ in, __bf16* __restrict__ out, int K, int N) {
  __shared__ float tile[32][33];
  int n0 = blockIdx.x * 32, k0 = blockIdx.y * 32;
  int tx = threadIdx.x & 31, ty = threadIdx.x >> 5;
#pragma unroll
  for (int r = 0; r < 32; r += 8)
    tile[r + ty][tx] = in[(size_t)(k0 + r + ty) * N + n0 + tx];
  __syncthreads();
#pragma unroll
  for (int r = 0; r < 32; r += 8)
    out[(size_t)(n0 + r + ty) * K + k0 + tx] = (__bf16)tile[tx][r + ty];
}

__global__ __launch_bounds__(256) void concat3_k(
    const float* __restrict__ a, const float* __restrict__ b,
    const float* __restrict__ c, float* __restrict__ dst) {
  int i = blockIdx.x * 256 + threadIdx.x;
  if (i < 1024) dst[i] = a[i];
  else if (i < 2048) dst[i] = b[i - 1024];
  else if (i < 3072) dst[i] = c[i - 2048];
}

// ---------------- RMSNorm: x f32 [rows][1024] -> bf16, * scale
__global__ __launch_bounds__(256) void rmsnorm_k(
    const float* __restrict__ x, const float* __restrict__ scale,
    __bf16* __restrict__ out) {
  int row = blockIdx.x, tid = threadIdx.x;
  f32x4 v = ((const f32x4*)(x + (size_t)row * DMODEL))[tid];
  float ss = v[0] * v[0] + v[1] * v[1] + v[2] * v[2] + v[3] * v[3];
#pragma unroll
  for (int off = 1; off < 64; off <<= 1) ss += __shfl_xor(ss, off, 64);
  __shared__ float part[4];
  if ((tid & 63) == 0) part[tid >> 6] = ss;
  __syncthreads();
  float tot = part[0] + part[1] + part[2] + part[3];
  float r = rsqrtf(tot * (1.0f / DMODEL) + 1e-6f);
  f32x4 s4 = ((const f32x4*)scale)[tid];
  bf16x4 o;
#pragma unroll
  for (int e = 0; e < 4; ++e) o[e] = (__bf16)(v[e] * r * s4[e]);
  ((bf16x4*)out)[(size_t)row * (DMODEL / 4) + tid] = o;
}

// ---------------- GEMM: C[M][N] = A[M][K](bf16) @ Bt[N][K]^T(bf16) + bias
// epilogue: optional silu(aux)*val, optional +resid, out bf16 or f32
template <int OUT_BF16, int RESID, int SILU>
__global__ __launch_bounds__(256, 2) void gemm_bt(
    const __bf16* __restrict__ A, const __bf16* __restrict__ Bt,
    const float* __restrict__ bias, const float* __restrict__ resid,
    const __bf16* __restrict__ aux, void* __restrict__ Cout,
    int M, int N, int K) {
  __shared__ __attribute__((aligned(16))) __bf16 As[128 * 64];
  __shared__ __attribute__((aligned(16))) __bf16 Bs[128 * 64];
  int tid = threadIdx.x, lane = tid & 63, wave = tid >> 6;
  int l15 = lane & 15, g4 = lane >> 4;
  int bm = blockIdx.y * 128, bn = blockIdx.x * 128;
  int wr = wave >> 1, wc = wave & 1;
  f32x4 acc[4][4] = {};
  int srow = lane >> 3, scol = (lane & 7) * 8;
  const __bf16* Abase = A + (size_t)bm * K;
  const __bf16* Bbase = Bt + (size_t)bn * K;

  for (int k0 = 0; k0 < K; k0 += 64) {
#pragma unroll
    for (int i = 0; i < 4; ++i) {
      int c = wave * 4 + i;
      int row = c * 8 + srow;
      gload_lds16(Abase + (size_t)row * K + k0 + scol, As + c * 512);
      gload_lds16(Bbase + (size_t)row * K + k0 + scol, Bs + c * 512);
    }
    __syncthreads();
#pragma unroll
    for (int ks = 0; ks < 2; ++ks) {
      bf16x8 af[4], bfr[4];
#pragma unroll
      for (int m = 0; m < 4; ++m)
        af[m] = *(const bf16x8*)(As + (wr * 64 + m * 16 + l15) * 64 + ks * 32 + g4 * 8);
#pragma unroll
      for (int n = 0; n < 4; ++n)
        bfr[n] = *(const bf16x8*)(Bs + (wc * 64 + n * 16 + l15) * 64 + ks * 32 + g4 * 8);
#pragma unroll
      for (int m = 0; m < 4; ++m)
#pragma unroll
        for (int n = 0; n < 4; ++n)
          acc[m][n] = __builtin_amdgcn_mfma_f32_16x16x32_bf16(af[m], bfr[n], acc[m][n], 0, 0, 0);
    }
    __syncthreads();
  }
  int r0 = bm + wr * 64 + g4 * 4;
  int c0 = bn + wc * 64 + l15;
#pragma unroll
  for (int n = 0; n < 4; ++n) {
    int c = c0 + n * 16;
    float bv = bias[c];
#pragma unroll
    for (int m = 0; m < 4; ++m) {
      int rb = r0 + m * 16;
#pragma unroll
      for (int rg = 0; rg < 4; ++rg) {
        int r = rb + rg;
        size_t idx = (size_t)r * N + c;
        float v = acc[m][n][rg] + bv;
        if (SILU) {
          float gg = (float)aux[idx];
          v *= gg / (1.0f + __expf(-gg));
        }
        if (RESID) v += resid[idx];
        if (OUT_BF16) ((__bf16*)Cout)[idx] = (__bf16)v;
        else ((float*)Cout)[idx] = v;
      }
    }
  }
}

// ---------------- causal flash attention over fused qkv [4096][3072] bf16
__global__ __launch_bounds__(256, 2) void attn_k(
    const __bf16* __restrict__ qkv, __bf16* __restrict__ ao) {
  __shared__ __attribute__((aligned(16))) __bf16 Ks[64 * 64];
  __shared__ __attribute__((aligned(16))) __bf16 Vt[64 * 64];
  __shared__ __attribute__((aligned(16))) __bf16 Pl[4][32 * 64];
  int tid = threadIdx.x, lane = tid & 63, w = tid >> 6;
  int l15 = lane & 15, g4 = lane >> 4;
  int qt = blockIdx.x, bh = blockIdx.y;
  int b = bh >> 4, h = bh & 15;
  int qb = qt * 128;
  const size_t rs3 = 3072;
  const __bf16* base = qkv + (size_t)b * S_LEN * rs3 + h * 64;

  bf16x8 qf[2][2];
#pragma unroll
  for (int m = 0; m < 2; ++m)
#pragma unroll
    for (int ks = 0; ks < 2; ++ks)
      qf[m][ks] = *(const bf16x8*)(base + (size_t)(qb + w * 32 + m * 16 + l15) * rs3 + ks * 32 + g4 * 8);

  f32x4 Oa[2][4] = {};
  float Mr[2][4], Lr[2][4];
#pragma unroll
  for (int m = 0; m < 2; ++m)
#pragma unroll
    for (int rg = 0; rg < 4; ++rg) { Mr[m][rg] = -1e30f; Lr[m][rg] = 0.f; }

  int nt = qb / 64 + 2;
  for (int t = 0; t < nt; ++t) {
    int kvb = t * 64;
    // stage K tile [64 keys][64 d] via global_load_lds
#pragma unroll
    for (int i = 0; i < 2; ++i) {
      int ch = w * 2 + i;
      int row = ch * 8 + (lane >> 3), col = (lane & 7) * 8;
      gload_lds16(base + 1024 + (size_t)(kvb + row) * rs3 + col, Ks + ch * 512);
    }
    // stage V transposed ([d][j]) via regs
#pragma unroll
    for (int i = 0; i < 2; ++i) {
      int ch = tid + i * 256;
      int j = ch >> 3, d0 = (ch & 7) * 8;
      bf16x8 vv = *(const bf16x8*)(base + 2048 + (size_t)(kvb + j) * rs3 + d0);
#pragma unroll
      for (int e = 0; e < 8; ++e) Vt[(d0 + e) * 64 + j] = vv[e];
    }
    __syncthreads();
    // S = Q K^T
    f32x4 sa[2][4] = {};
#pragma unroll
    for (int ks = 0; ks < 2; ++ks) {
      bf16x8 kf[4];
#pragma unroll
      for (int n = 0; n < 4; ++n)
        kf[n] = *(const bf16x8*)(Ks + (n * 16 + l15) * 64 + ks * 32 + g4 * 8);
#pragma unroll
      for (int m = 0; m < 2; ++m)
#pragma unroll
        for (int n = 0; n < 4; ++n)
          sa[m][n] = __builtin_amdgcn_mfma_f32_16x16x32_bf16(qf[m][ks], kf[n], sa[m][n], 0, 0, 0);
    }
    // online softmax (rows: m*16 + 4*g4 + rg; cols: kvb + n*16 + l15)
#pragma unroll
    for (int m = 0; m < 2; ++m) {
#pragma unroll
      for (int rg = 0; rg < 4; ++rg) {
        int q = qb + w * 32 + m * 16 + g4 * 4 + rg;
        float mx = -1e30f;
#pragma unroll
        for (int n = 0; n < 4; ++n) {
          float s = sa[m][n][rg] * 0.125f;
          int j = kvb + n * 16 + l15;
          s = (j <= q) ? s : -1e30f;
          sa[m][n][rg] = s;
          mx = fmaxf(mx, s);
        }
#pragma unroll
        for (int off = 1; off < 16; off <<= 1) mx = fmaxf(mx, __shfl_xor(mx, off, 64));
        float nm = fmaxf(Mr[m][rg], mx);
        float sc = __expf(Mr[m][rg] - nm);
        Mr[m][rg] = nm;
        float rsum = 0.f;
#pragma unroll
        for (int n = 0; n < 4; ++n) {
          float p = __expf(sa[m][n][rg] - nm);
          rsum += p;
          Pl[w][(m * 16 + g4 * 4 + rg) * 64 + n * 16 + l15] = (__bf16)p;
        }
#pragma unroll
        for (int off = 1; off < 16; off <<= 1) rsum += __shfl_xor(rsum, off, 64);
        Lr[m][rg] = Lr[m][rg] * sc + rsum;
#pragma unroll
        for (int dn = 0; dn < 4; ++dn) Oa[m][dn][rg] *= sc;
      }
    }
    __syncthreads();
    // O += P V   (A-frag from Pl, B-frag from Vt, shared sigma = 8g+e)
#pragma unroll
    for (int ks = 0; ks < 2; ++ks) {
      bf16x8 pa[2], vf[4];
#pragma unroll
      for (int m = 0; m < 2; ++m)
        pa[m] = *(const bf16x8*)(&Pl[w][(m * 16 + l15) * 64 + ks * 32 + g4 * 8]);
#pragma unroll
      for (int dn = 0; dn < 4; ++dn)
        vf[dn] = *(const bf16x8*)(Vt + (dn * 16 + l15) * 64 + ks * 32 + g4 * 8);
#pragma unroll
      for (int m = 0; m < 2; ++m)
#pragma unroll
        for (int dn = 0; dn < 4; ++dn)
          Oa[m][dn] = __builtin_amdgcn_mfma_f32_16x16x32_bf16(pa[m], vf[dn], Oa[m][dn], 0, 0, 0);
    }
    __syncthreads();
  }
  __bf16* aobase = ao + (size_t)b * S_LEN * DMODEL + h * 64;
#pragma unroll
  for (int m = 0; m < 2; ++m) {
#pragma unroll
    for (int rg = 0; rg < 4; ++rg) {
      int q = qb + w * 32 + m * 16 + g4 * 4 + rg;
      float rl = 1.0f / Lr[m][rg];
#pragma unroll
      for (int dn = 0; dn < 4; ++dn)
        aobase[(size_t)q * DMODEL + dn * 16 + l15] = (__bf16)(Oa[m][dn][rg] * rl);
    }
  }
}

// ---------------- host side ----------------
#define OFF_WQKV 0
#define OFF_WO 6291456
#define OFF_WG 8388608
#define OFF_WU 16777216
#define OFF_WD 25165824
#define OFF_BQKV 33554432
#define OFF_H 33570816
#define OFF_QKV 41959424
#define OFF_AO 67125248
#define OFF_G OFF_QKV
#define OFF_T 75513856
#define OFF_X2 109068288

extern "C" void kernel_launch(void* const* d_in, const int* in_sizes, int n_in,
                              void* d_out, int out_size, void* d_ws, size_t ws_size,
                              hipStream_t stream) {
  (void)in_sizes; (void)n_in; (void)out_size; (void)ws_size;
  const float* x = (const float*)d_in[0];
  const float* attn_scale = (const float*)d_in[2];
  const float* q_w = (const float*)d_in[3];
  const float* q_b = (const float*)d_in[4];
  const float* k_w = (const float*)d_in[5];
  const float* k_b = (const float*)d_in[6];
  const float* v_w = (const float*)d_in[7];
  const float* v_b = (const float*)d_in[8];
  const float* o_w = (const float*)d_in[9];
  const float* o_b = (const float*)d_in[10];
  const float* ffn_scale = (const float*)d_in[11];
  const float* gate_w = (const float*)d_in[12];
  const float* gate_b = (const float*)d_in[13];
  const float* up_w = (const float*)d_in[14];
  const float* up_b = (const float*)d_in[15];
  const float* down_w = (const float*)d_in[16];
  const float* down_b = (const float*)d_in[17];

  char* ws = (char*)d_ws;
  __bf16* wqkv = (__bf16*)(ws + OFF_WQKV);
  __bf16* wo = (__bf16*)(ws + OFF_WO);
  __bf16* wg = (__bf16*)(ws + OFF_WG);
  __bf16* wu = (__bf16*)(ws + OFF_WU);
  __bf16* wd = (__bf16*)(ws + OFF_WD);
  float* bqkv = (float*)(ws + OFF_BQKV);
  __bf16* hbuf = (__bf16*)(ws + OFF_H);
  __bf16* qkvbuf = (__bf16*)(ws + OFF_QKV);
  __bf16* aobuf = (__bf16*)(ws + OFF_AO);
  __bf16* gbuf = (__bf16*)(ws + OFF_G);
  __bf16* tbuf = (__bf16*)(ws + OFF_T);
  float* x2 = (float*)(ws + OFF_X2);

  dim3 blk(256);
  // weight prep
  transpose_cast_k<<<dim3(32, 32), blk, 0, stream>>>(q_w, wqkv, 1024, 1024);
  transpose_cast_k<<<dim3(32, 32), blk, 0, stream>>>(k_w, wqkv + 1024 * 1024, 1024, 1024);
  transpose_cast_k<<<dim3(32, 32), blk, 0, stream>>>(v_w, wqkv + 2 * 1024 * 1024, 1024, 1024);
  transpose_cast_k<<<dim3(32, 32), blk, 0, stream>>>(o_w, wo, 1024, 1024);
  transpose_cast_k<<<dim3(128, 32), blk, 0, stream>>>(gate_w, wg, 1024, 4096);
  transpose_cast_k<<<dim3(128, 32), blk, 0, stream>>>(up_w, wu, 1024, 4096);
  transpose_cast_k<<<dim3(32, 128), blk, 0, stream>>>(down_w, wd, 4096, 1024);
  concat3_k<<<12, blk, 0, stream>>>(q_b, k_b, v_b, bqkv);
  // attn path
  rmsnorm_k<<<4096, blk, 0, stream>>>(x, attn_scale, hbuf);
  gemm_bt<1, 0, 0><<<dim3(24, 32), blk, 0, stream>>>(hbuf, wqkv, bqkv, nullptr, nullptr, qkvbuf, 4096, 3072, 1024);
  attn_k<<<dim3(16, 32), blk, 0, stream>>>(qkvbuf, aobuf);
  gemm_bt<0, 1, 0><<<dim3(8, 32), blk, 0, stream>>>(aobuf, wo, o_b, x, nullptr, x2, 4096, 1024, 1024);
  // ffn path
  rmsnorm_k<<<4096, blk, 0, stream>>>(x2, ffn_scale, hbuf);
  gemm_bt<1, 0, 0><<<dim3(32, 32), blk, 0, stream>>>(hbuf, wg, gate_b, nullptr, nullptr, gbuf, 4096, 4096, 1024);
  gemm_bt<1, 0, 1><<<dim3(32, 32), blk, 0, stream>>>(hbuf, wu, up_b, nullptr, gbuf, tbuf, 4096, 4096, 1024);
  gemm_bt<0, 1, 0><<<dim3(8, 32), blk, 0, stream>>>(tbuf, wd, down_b, x2, nullptr, (float*)d_out, 4096, 1024, 4096);
}